// Round 12
// baseline (1147.545 us; speedup 1.0000x reference)
//
#include <hip/hip_runtime.h>
#include <math.h>
#include <stdint.h>

#define N_CTX 4096
#define DIM 512
#define NPERS 16
#define KTOT (NPERS * DIM)   // 8192
#define EPS_NN 0.1f
#define TOPK_K 30

#define DELTA 1e-3f          // ambiguity margin (>> worst approx-vs-exact error)
#define CAP 64               // max candidates per row

#define BM 128               // MFMA output tile
#define BK 64                // K-step (bf16 elems)
#define NKSTEP (KTOT / BK)   // 128
#define CHUNK 16384          // bytes per (panel, k-step) LDS image

typedef __attribute__((ext_vector_type(8))) short bfrag;   // 8 bf16 = 4 VGPR
typedef __attribute__((ext_vector_type(4))) float f32x4;

// round-to-nearest-even float -> bf16 bits
__device__ __forceinline__ unsigned short f2bf(float f) {
  unsigned u = __float_as_uint(f);
  unsigned r = u + 0x7FFFu + ((u >> 16) & 1u);
  return (unsigned short)(r >> 16);
}

#define SWZ(r, b) ((b) ^ (((r) & 7) << 4))

// stage 1 KB: 64 lanes x 16 B. ldst = wave-uniform LDS base; HW adds lane*16.
__device__ __forceinline__ void stage1k(const char* gsrc, char* ldst, int lane) {
#if __has_builtin(__builtin_amdgcn_global_load_lds)
  __builtin_amdgcn_global_load_lds(
      (const __attribute__((address_space(1))) unsigned int*)(uintptr_t)(gsrc + lane * 16),
      (__attribute__((address_space(3))) unsigned int*)(uintptr_t)ldst, 16, 0, 0);
#else
  *reinterpret_cast<uint4*>(ldst + lane * 16) =
      *reinterpret_cast<const uint4*>(gsrc + lane * 16);
#endif
}

// ---------------------------------------------------------------------------
// Kernel 1: invr[p][n] = 0.25 / max(||context[n] * weight[p]||, 1e-12)
// UNCHANGED (bit-identical invr feeds split, fallback GEMM and exact repair).
// ---------------------------------------------------------------------------
__global__ __launch_bounds__(256) void norms_kernel(
    const float* __restrict__ ctx, const float* __restrict__ w,
    float* __restrict__ invr) {
  int wid = threadIdx.x >> 6;
  int lane = threadIdx.x & 63;
  int gid = blockIdx.x * 4 + wid;          // 0 .. 65535
  int p = gid >> 12;
  int n = gid & (N_CTX - 1);
  const float4* c4 = reinterpret_cast<const float4*>(ctx + (size_t)n * DIM + lane * 8);
  const float4* w4 = reinterpret_cast<const float4*>(w + (size_t)p * DIM + lane * 8);
  float4 c0 = c4[0], c1 = c4[1];
  float4 w0 = w4[0], w1 = w4[1];
  float s = 0.f, v;
  v = c0.x * w0.x; s = fmaf(v, v, s);
  v = c0.y * w0.y; s = fmaf(v, v, s);
  v = c0.z * w0.z; s = fmaf(v, v, s);
  v = c0.w * w0.w; s = fmaf(v, v, s);
  v = c1.x * w1.x; s = fmaf(v, v, s);
  v = c1.y * w1.y; s = fmaf(v, v, s);
  v = c1.z * w1.z; s = fmaf(v, v, s);
  v = c1.w * w1.w; s = fmaf(v, v, s);
#pragma unroll
  for (int off = 32; off; off >>= 1) s += __shfl_down(s, off, 64);
  if (lane == 0) invr[(size_t)p * N_CTX + n] = 0.25f / fmaxf(sqrtf(s), 1e-12f);
}

// ---------------------------------------------------------------------------
// Kernel 1b: split F = hi + lo into panel-swizzled LDS-image layout.
// UNCHANGED from R11.
// ---------------------------------------------------------------------------
__global__ __launch_bounds__(256) void split_kernel(
    const float* __restrict__ ctx, const float* __restrict__ w,
    const float* __restrict__ invr, unsigned short* __restrict__ Fhi,
    unsigned short* __restrict__ Flo) {
  const int tid = blockIdx.x * 256 + threadIdx.x;   // 0 .. 4096*64-1
  const int n = tid >> 6;
  const int db = tid & 63;                // 8-col block within the 512-dim
  const int d0 = db * 8;
  const int P = n >> 7;                   // panel
  const int r = n & 127;                  // row within panel
  const int sl = db & 7;                  // 16B slot within k-step chunk
  const int swzoff = r * 128 + ((sl * 16) ^ ((r & 7) << 4));

  const float4 c0 = *reinterpret_cast<const float4*>(ctx + (size_t)n * DIM + d0);
  const float4 c1 = *reinterpret_cast<const float4*>(ctx + (size_t)n * DIM + d0 + 4);

#pragma unroll
  for (int p = 0; p < NPERS; ++p) {
    const float4 w0 = *reinterpret_cast<const float4*>(w + (size_t)p * DIM + d0);
    const float4 w1 = *reinterpret_cast<const float4*>(w + (size_t)p * DIM + d0 + 4);
    const float sc = invr[(size_t)p * N_CTX + n];

    float f[8] = {c0.x * w0.x * sc, c0.y * w0.y * sc, c0.z * w0.z * sc, c0.w * w0.w * sc,
                  c1.x * w1.x * sc, c1.y * w1.y * sc, c1.z * w1.z * sc, c1.w * w1.w * sc};
    unsigned hb[8], lb[8];
#pragma unroll
    for (int j = 0; j < 8; ++j) {
      hb[j] = f2bf(f[j]);
      float hf = __uint_as_float(hb[j] << 16);
      lb[j] = f2bf(f[j] - hf);
    }
    uint4 hv = make_uint4(hb[0] | (hb[1] << 16), hb[2] | (hb[3] << 16),
                          hb[4] | (hb[5] << 16), hb[6] | (hb[7] << 16));
    uint4 lv = make_uint4(lb[0] | (lb[1] << 16), lb[2] | (lb[3] << 16),
                          lb[4] | (lb[5] << 16), lb[6] | (lb[7] << 16));
    const int s = p * 8 + (db >> 3);      // k-step index
    const size_t base = (size_t)(P * 128 + s) * CHUNK + swzoff;
    *reinterpret_cast<uint4*>((char*)Fhi + base) = hv;
    *reinterpret_cast<uint4*>((char*)Flo + base) = lv;
  }
}

// ---------------------------------------------------------------------------
// Kernel 2 (fast): att = F F^T via bf16 MFMA, 3 products (hh, hl, lh).
// UNCHANGED from R10/R11 (496 us, MfmaUtil 38%, validated).
// ---------------------------------------------------------------------------
__global__ __launch_bounds__(256, 2) void att_gemm_fast(
    const unsigned short* __restrict__ Fhi, const unsigned short* __restrict__ Flo,
    float* __restrict__ out) {
  int bid = blockIdx.x;
  int by = 0;
  while (bid >= (by + 1) * 32 - ((by + 1) * by) / 2) ++by;
  const int bx = by + (bid - (by * 32 - (by * (by - 1)) / 2));

  __shared__ __align__(16) char Ahi[CHUNK];
  __shared__ __align__(16) char Alo[CHUNK];
  __shared__ __align__(16) char Bhi[CHUNK];
  __shared__ __align__(16) char Blo[CHUNK];

  const int t = threadIdx.x;
  const int lane = t & 63, wid = t >> 6;
  const int wr = wid >> 1, wc = wid & 1;
  const int woff = __builtin_amdgcn_readfirstlane(wid * 4096);

  const char* gAh = (const char*)Fhi + (size_t)by * NKSTEP * CHUNK + woff;
  const char* gAl = (const char*)Flo + (size_t)by * NKSTEP * CHUNK + woff;
  const char* gBh = (const char*)Fhi + (size_t)bx * NKSTEP * CHUNK + woff;
  const char* gBl = (const char*)Flo + (size_t)bx * NKSTEP * CHUNK + woff;

  f32x4 acc[4][4] = {};

  for (int s = 0; s < NKSTEP; ++s) {
    const size_t so = (size_t)s * CHUNK;
#pragma unroll
    for (int i = 0; i < 4; ++i) {
      stage1k(gAh + so + i * 1024, Ahi + woff + i * 1024, lane);
      stage1k(gAl + so + i * 1024, Alo + woff + i * 1024, lane);
      stage1k(gBh + so + i * 1024, Bhi + woff + i * 1024, lane);
      stage1k(gBl + so + i * 1024, Blo + woff + i * 1024, lane);
    }
    __syncthreads();   // vmcnt drained before barrier: staged data visible

#pragma unroll
    for (int ks = 0; ks < 2; ++ks) {
      const int kb = ks * 64 + (lane >> 4) * 16;
      bfrag ah[4], al[4], bh[4], bl[4];
#pragma unroll
      for (int m = 0; m < 4; ++m) {
        const int r = wr * 64 + m * 16 + (lane & 15);
        const int off = r * 128 + SWZ(r, kb);
        ah[m] = *reinterpret_cast<const bfrag*>(Ahi + off);
        al[m] = *reinterpret_cast<const bfrag*>(Alo + off);
      }
#pragma unroll
      for (int n2 = 0; n2 < 4; ++n2) {
        const int r = wc * 64 + n2 * 16 + (lane & 15);
        const int off = r * 128 + SWZ(r, kb);
        bh[n2] = *reinterpret_cast<const bfrag*>(Bhi + off);
        bl[n2] = *reinterpret_cast<const bfrag*>(Blo + off);
      }
#pragma unroll
      for (int m = 0; m < 4; ++m)
#pragma unroll
        for (int n2 = 0; n2 < 4; ++n2) {
          acc[m][n2] = __builtin_amdgcn_mfma_f32_16x16x32_bf16(ah[m], bh[n2], acc[m][n2], 0, 0, 0);
          acc[m][n2] = __builtin_amdgcn_mfma_f32_16x16x32_bf16(ah[m], bl[n2], acc[m][n2], 0, 0, 0);
          acc[m][n2] = __builtin_amdgcn_mfma_f32_16x16x32_bf16(al[m], bh[n2], acc[m][n2], 0, 0, 0);
        }
    }
    __syncthreads();   // all waves done reading before next overwrite
  }

  const int Ro = by * BM, Co = bx * BM;
  const int col = lane & 15, rq = (lane >> 4) * 4;
#pragma unroll
  for (int m = 0; m < 4; ++m)
#pragma unroll
    for (int n2 = 0; n2 < 4; ++n2) {
      const int gr = Ro + wr * 64 + m * 16 + rq;
      const int gc = Co + wc * 64 + n2 * 16 + col;
#pragma unroll
      for (int j = 0; j < 4; ++j)
        out[(size_t)(gr + j) * N_CTX + gc] = acc[m][n2][j];
      if (bx != by) {
        *reinterpret_cast<float4*>(out + (size_t)gc * N_CTX + gr) =
            make_float4(acc[m][n2][0], acc[m][n2][1], acc[m][n2][2], acc[m][n2][3]);
      }
    }
}

// ---------------------------------------------------------------------------
// Kernel 2 (fallback): on-the-fly split + MFMA (used only if ws too small).
// ---------------------------------------------------------------------------
__device__ __forceinline__ void stage_half(char* __restrict__ hi_base,
                                           char* __restrict__ lo_base,
                                           const float4* cv, const float4* wv,
                                           float s, int r, int h) {
  unsigned hu[16], lu[16];
#pragma unroll
  for (int i = 0; i < 8; ++i) {
    float f[4] = {cv[i].x * wv[i].x * s, cv[i].y * wv[i].y * s,
                  cv[i].z * wv[i].z * s, cv[i].w * wv[i].w * s};
    unsigned hb[4], lb[4];
#pragma unroll
    for (int j = 0; j < 4; ++j) {
      hb[j] = f2bf(f[j]);
      float hf = __uint_as_float(hb[j] << 16);
      lb[j] = f2bf(f[j] - hf);
    }
    hu[2 * i] = hb[0] | (hb[1] << 16);
    hu[2 * i + 1] = hb[2] | (hb[3] << 16);
    lu[2 * i] = lb[0] | (lb[1] << 16);
    lu[2 * i + 1] = lb[2] | (lb[3] << 16);
  }
#pragma unroll
  for (int c = 0; c < 4; ++c) {
    int boff = r * 128 + SWZ(r, h * 64 + c * 16);
    *reinterpret_cast<uint4*>(hi_base + boff) =
        make_uint4(hu[4 * c], hu[4 * c + 1], hu[4 * c + 2], hu[4 * c + 3]);
    *reinterpret_cast<uint4*>(lo_base + boff) =
        make_uint4(lu[4 * c], lu[4 * c + 1], lu[4 * c + 2], lu[4 * c + 3]);
  }
}

__global__ __launch_bounds__(256, 2) void att_gemm(
    const float* __restrict__ ctx, const float* __restrict__ w,
    const float* __restrict__ invr, float* __restrict__ out) {
  const int bx = blockIdx.x, by = blockIdx.y;
  if (by > bx) return;

  __shared__ __align__(16) char Ahi[BM * 128];
  __shared__ __align__(16) char Alo[BM * 128];
  __shared__ __align__(16) char Bhi[BM * 128];
  __shared__ __align__(16) char Blo[BM * 128];

  const int t = threadIdx.x;
  const int lane = t & 63, wid = t >> 6;
  const int wr = wid >> 1, wc = wid & 1;
  const int Ro = by * BM, Co = bx * BM;
  const int srow = t >> 1;
  const int sh = t & 1;

  f32x4 acc[4][4] = {};

  for (int k0 = 0; k0 < KTOT; k0 += BK) {
    const int p = k0 >> 9;
    const int d0 = (k0 & (DIM - 1)) + sh * 32;

    float4 cva[8], cvb[8], wv[8];
    const float* wrow = w + (size_t)p * DIM + d0;
    const float* arow = ctx + (size_t)(Ro + srow) * DIM + d0;
    const float* brow = ctx + (size_t)(Co + srow) * DIM + d0;
#pragma unroll
    for (int i = 0; i < 8; ++i) {
      wv[i] = *reinterpret_cast<const float4*>(wrow + 4 * i);
      cva[i] = *reinterpret_cast<const float4*>(arow + 4 * i);
      cvb[i] = *reinterpret_cast<const float4*>(brow + 4 * i);
    }
    const float sA = invr[(size_t)p * N_CTX + Ro + srow];
    const float sB = invr[(size_t)p * N_CTX + Co + srow];

    __syncthreads();
    stage_half(Ahi, Alo, cva, wv, sA, srow, sh);
    stage_half(Bhi, Blo, cvb, wv, sB, srow, sh);
    __syncthreads();

#pragma unroll
    for (int ks = 0; ks < 2; ++ks) {
      const int kb = ks * 64 + (lane >> 4) * 16;
      bfrag ah[4], al[4], bh[4], bl[4];
#pragma unroll
      for (int m = 0; m < 4; ++m) {
        const int r = wr * 64 + m * 16 + (lane & 15);
        const int off = r * 128 + SWZ(r, kb);
        ah[m] = *reinterpret_cast<const bfrag*>(Ahi + off);
        al[m] = *reinterpret_cast<const bfrag*>(Alo + off);
      }
#pragma unroll
      for (int n = 0; n < 4; ++n) {
        const int r = wc * 64 + n * 16 + (lane & 15);
        const int off = r * 128 + SWZ(r, kb);
        bh[n] = *reinterpret_cast<const bfrag*>(Bhi + off);
        bl[n] = *reinterpret_cast<const bfrag*>(Blo + off);
      }
#pragma unroll
      for (int m = 0; m < 4; ++m)
#pragma unroll
        for (int n = 0; n < 4; ++n) {
          acc[m][n] = __builtin_amdgcn_mfma_f32_16x16x32_bf16(ah[m], bh[n], acc[m][n], 0, 0, 0);
          acc[m][n] = __builtin_amdgcn_mfma_f32_16x16x32_bf16(ah[m], bl[n], acc[m][n], 0, 0, 0);
          acc[m][n] = __builtin_amdgcn_mfma_f32_16x16x32_bf16(al[m], bh[n], acc[m][n], 0, 0, 0);
        }
    }
  }

  const int col = lane & 15, rq = (lane >> 4) * 4;
#pragma unroll
  for (int m = 0; m < 4; ++m)
#pragma unroll
    for (int n = 0; n < 4; ++n) {
      const int gr = Ro + wr * 64 + m * 16 + rq;
      const int gc = Co + wc * 64 + n * 16 + col;
#pragma unroll
      for (int j = 0; j < 4; ++j)
        out[(size_t)(gr + j) * N_CTX + gc] = acc[m][n][j];
      if (bx != by) {
        *reinterpret_cast<float4*>(out + (size_t)gc * N_CTX + gr) =
            make_float4(acc[m][n][0], acc[m][n][1], acc[m][n][2], acc[m][n][3]);
      }
    }
}

// ---------------------------------------------------------------------------
// Kernel 3 (fused): scan + exact repair + select, one block per row.
// R12 changes vs R11 scan/repair pair:
//  - COALESCED mapping: thread t owns float4s at (i*256+t) -> every wave
//    load/store is 64 x 16 B contiguous (was 64 distinct 64-B segments).
//  - candidates kept in LDS; repair runs in the same block after the masked
//    row is stored (no candM/cnt_g global traffic, no 4th kernel launch).
//  - classification semantics and exact-repair fmaf chain are VERBATIM from
//    R11 (bit-identical mask).
// ---------------------------------------------------------------------------
__global__ __launch_bounds__(256) void topk_fused(
    float* __restrict__ att, const float* __restrict__ ctx,
    const float* __restrict__ w, const float* __restrict__ invr) {
  __shared__ unsigned red[4];
  __shared__ int lcnt, lg;
  __shared__ float te_s[CAP];
  __shared__ int m_s[CAP];

  const int n = blockIdx.x;
  const int t = threadIdx.x;
  const int wid = t >> 6, lane = t & 63;
  float* row = att + (size_t)n * N_CTX;

  float ar[16], tr[16];
  unsigned ur[16];
#pragma unroll
  for (int i = 0; i < 4; ++i) {
    float4 v4 = *reinterpret_cast<const float4*>(row + (size_t)(i * 256 + t) * 4);
    float tmp[4] = {v4.x, v4.y, v4.z, v4.w};
#pragma unroll
    for (int j = 0; j < 4; ++j) {
      float a = tmp[j];
      float tt = (a > EPS_NN) ? a : 0.0f;
      ar[i * 4 + j] = a;
      tr[i * 4 + j] = tt;
      ur[i * 4 + j] = __float_as_uint(tt);
    }
  }

  // binary search: smallest u with count(bits > u) < K  => u = bits(30th)
  unsigned lo = 0u, hi = 0x7F800000u;
  while (lo < hi) {
    unsigned mid = lo + ((hi - lo) >> 1);
    unsigned c = 0;
#pragma unroll
    for (int i = 0; i < 16; ++i) c += (ur[i] > mid) ? 1u : 0u;
#pragma unroll
    for (int off = 32; off; off >>= 1) c += __shfl_down(c, off, 64);
    if (lane == 0) red[wid] = c;
    __syncthreads();
    unsigned tot = red[0] + red[1] + red[2] + red[3];
    __syncthreads();
    if (tot < TOPK_K) hi = mid; else lo = mid + 1;
  }
  const float vk = __uint_as_float(lo);
  const bool nearEps = (vk <= EPS_NN + 2.0f * DELTA);

  if (t == 0) { lcnt = 0; lg = 0; }
  __syncthreads();

  unsigned myg = 0;
#pragma unroll
  for (int i = 0; i < 16; ++i) {
    const int m = (i * 256 + t) * 4 + (0);  // base; per-element below
    (void)m;
  }
#pragma unroll
  for (int i = 0; i < 16; ++i) {
    const int blk = i >> 2, j = i & 3;
    const int m = (blk * 256 + t) * 4 + j;
    const float a = ar[i], tt = tr[i];
    const bool isEps = fabsf(a - EPS_NN) <= DELTA;
    const bool isOrd = (tt > 0.f) && (fabsf(tt - vk) <= DELTA);
    const bool cand = isOrd || (isEps && nearEps);
    const bool defIn = (tt > vk + DELTA) && !cand;
    tr[i] = defIn ? tt : 0.f;
    myg += defIn ? 1u : 0u;
    if (cand) {
      int pos = atomicAdd(&lcnt, 1);
      if (pos < CAP) m_s[pos] = m;
    }
  }
#pragma unroll
  for (int off = 32; off; off >>= 1) myg += __shfl_down(myg, off, 64);
  if (lane == 0) atomicAdd(&lg, (int)myg);

  // store masked row (coalesced)
#pragma unroll
  for (int i = 0; i < 4; ++i) {
    *reinterpret_cast<float4*>(row + (size_t)(i * 256 + t) * 4) =
        make_float4(tr[i * 4], tr[i * 4 + 1], tr[i * 4 + 2], tr[i * 4 + 3]);
  }
  __syncthreads();   // lcnt/lg final; row stores retired (waitcnt drain)

  const int c = (lcnt < CAP) ? lcnt : CAP;
  if (c == 0) return;
  const int slots = TOPK_K - lg;

  // exact repair: thread j < c recomputes candidate j with the LOCKED chain
  // ((cn*w)*sA vs (cm*w)*sB, k ascending via fmaf) -> bit-identical to R2.
  const int j = t;
  if (j < c) {
    const int m = m_s[j];
    const float4* cn4 = reinterpret_cast<const float4*>(ctx + (size_t)n * DIM);
    const float4* cm4 = reinterpret_cast<const float4*>(ctx + (size_t)m * DIM);
    float e = 0.f;
    for (int p = 0; p < NPERS; ++p) {
      const float sA = invr[(size_t)p * N_CTX + n];
      const float sB = invr[(size_t)p * N_CTX + m];
      const float4* w4 = reinterpret_cast<const float4*>(w + (size_t)p * DIM);
#pragma unroll 4
      for (int q = 0; q < DIM / 4; ++q) {
        const float4 a = cn4[q], b = cm4[q], ww = w4[q];
        e = fmaf((a.x * ww.x) * sA, (b.x * ww.x) * sB, e);
        e = fmaf((a.y * ww.y) * sA, (b.y * ww.y) * sB, e);
        e = fmaf((a.z * ww.z) * sA, (b.z * ww.z) * sB, e);
        e = fmaf((a.w * ww.w) * sA, (b.w * ww.w) * sB, e);
      }
    }
    te_s[j] = (e > EPS_NN) ? e : 0.f;
  }
  __syncthreads();

  if (j < c) {
    const int m = m_s[j];
    const float te = te_s[j];
    int rank = 0;
    for (int i = 0; i < c; ++i) {
      if (i == j) continue;
      rank += ((te_s[i] > te) || (te_s[i] == te && m_s[i] < m)) ? 1 : 0;
    }
    if (rank < slots) row[m] = te;   // patch after barrier: ordered vs zero-store
  }
}

// ---------------------------------------------------------------------------
extern "C" void kernel_launch(void* const* d_in, const int* in_sizes, int n_in,
                              void* d_out, int out_size, void* d_ws, size_t ws_size,
                              hipStream_t stream) {
  const float* ctx = (const float*)d_in[0];   // (4096, 512)
  const float* w   = (const float*)d_in[1];   // (16, 512)
  float* out = (float*)d_out;                 // (4096, 4096)

  // ws: invr (256 KB) | Fhi (64 MB) | Flo (64 MB)
  const size_t OFF_FHI = 262144;
  const size_t FSZ = (size_t)32 * NKSTEP * CHUNK;  // 67108864
  float* invr = (float*)d_ws;
  unsigned short* Fhi = (unsigned short*)((char*)d_ws + OFF_FHI);
  unsigned short* Flo = (unsigned short*)((char*)d_ws + OFF_FHI + FSZ);

  norms_kernel<<<(NPERS * N_CTX) / 4, 256, 0, stream>>>(ctx, w, invr);

  if (ws_size >= OFF_FHI + 2 * FSZ) {
    split_kernel<<<(N_CTX * 64) / 256, 256, 0, stream>>>(ctx, w, invr, Fhi, Flo);
    att_gemm_fast<<<528, 256, 0, stream>>>(Fhi, Flo, out);
  } else {
    dim3 grid(N_CTX / BM, N_CTX / BM);
    att_gemm<<<grid, 256, 0, stream>>>(ctx, w, invr, out);
  }

  topk_fused<<<N_CTX, 256, 0, stream>>>(out, ctx, w, invr);
}

// Round 13
// 1024.932 us; speedup vs baseline: 1.1196x; 1.1196x over previous
//
#include <hip/hip_runtime.h>
#include <math.h>
#include <stdint.h>

#define N_CTX 4096
#define DIM 512
#define NPERS 16
#define KTOT (NPERS * DIM)   // 8192
#define EPS_NN 0.1f
#define TOPK_K 30

#define DELTA 3e-4f          // ambiguity margin (>= 12x the 2*eps ~ 2.4e-5 bound)
#define CAP 64               // max candidates per row

#define BM 128               // MFMA output tile
#define BK 64                // K-step (bf16 elems)
#define NKSTEP (KTOT / BK)   // 128
#define CHUNK 16384          // bytes per (panel, k-step) LDS image

typedef __attribute__((ext_vector_type(8))) short bfrag;   // 8 bf16 = 4 VGPR
typedef __attribute__((ext_vector_type(4))) float f32x4;

// round-to-nearest-even float -> bf16 bits
__device__ __forceinline__ unsigned short f2bf(float f) {
  unsigned u = __float_as_uint(f);
  unsigned r = u + 0x7FFFu + ((u >> 16) & 1u);
  return (unsigned short)(r >> 16);
}

#define SWZ(r, b) ((b) ^ (((r) & 7) << 4))

// stage 1 KB: 64 lanes x 16 B. ldst = wave-uniform LDS base; HW adds lane*16.
__device__ __forceinline__ void stage1k(const char* gsrc, char* ldst, int lane) {
#if __has_builtin(__builtin_amdgcn_global_load_lds)
  __builtin_amdgcn_global_load_lds(
      (const __attribute__((address_space(1))) unsigned int*)(uintptr_t)(gsrc + lane * 16),
      (__attribute__((address_space(3))) unsigned int*)(uintptr_t)ldst, 16, 0, 0);
#else
  *reinterpret_cast<uint4*>(ldst + lane * 16) =
      *reinterpret_cast<const uint4*>(gsrc + lane * 16);
#endif
}

// ---------------------------------------------------------------------------
// Kernel 1: invr[p][n] = 0.25 / max(||context[n] * weight[p]||, 1e-12)
// UNCHANGED (bit-identical invr feeds split, fallback GEMM and exact repair).
// ---------------------------------------------------------------------------
__global__ __launch_bounds__(256) void norms_kernel(
    const float* __restrict__ ctx, const float* __restrict__ w,
    float* __restrict__ invr) {
  int wid = threadIdx.x >> 6;
  int lane = threadIdx.x & 63;
  int gid = blockIdx.x * 4 + wid;          // 0 .. 65535
  int p = gid >> 12;
  int n = gid & (N_CTX - 1);
  const float4* c4 = reinterpret_cast<const float4*>(ctx + (size_t)n * DIM + lane * 8);
  const float4* w4 = reinterpret_cast<const float4*>(w + (size_t)p * DIM + lane * 8);
  float4 c0 = c4[0], c1 = c4[1];
  float4 w0 = w4[0], w1 = w4[1];
  float s = 0.f, v;
  v = c0.x * w0.x; s = fmaf(v, v, s);
  v = c0.y * w0.y; s = fmaf(v, v, s);
  v = c0.z * w0.z; s = fmaf(v, v, s);
  v = c0.w * w0.w; s = fmaf(v, v, s);
  v = c1.x * w1.x; s = fmaf(v, v, s);
  v = c1.y * w1.y; s = fmaf(v, v, s);
  v = c1.z * w1.z; s = fmaf(v, v, s);
  v = c1.w * w1.w; s = fmaf(v, v, s);
#pragma unroll
  for (int off = 32; off; off >>= 1) s += __shfl_down(s, off, 64);
  if (lane == 0) invr[(size_t)p * N_CTX + n] = 0.25f / fmaxf(sqrtf(s), 1e-12f);
}

// ---------------------------------------------------------------------------
// Kernel 1b: split F = hi + lo into panel-swizzled LDS-image layout, and
// (R13) optionally materialize F in fp32 row-major [n][8192] — the exact
// staged values (c*w)*s that the locked R2 chain consumes.
// ---------------------------------------------------------------------------
__global__ __launch_bounds__(256) void split_kernel(
    const float* __restrict__ ctx, const float* __restrict__ w,
    const float* __restrict__ invr, unsigned short* __restrict__ Fhi,
    unsigned short* __restrict__ Flo, float* __restrict__ F32) {
  const int tid = blockIdx.x * 256 + threadIdx.x;   // 0 .. 4096*64-1
  const int n = tid >> 6;
  const int db = tid & 63;                // 8-col block within the 512-dim
  const int d0 = db * 8;
  const int P = n >> 7;                   // panel
  const int r = n & 127;                  // row within panel
  const int sl = db & 7;                  // 16B slot within k-step chunk
  const int swzoff = r * 128 + ((sl * 16) ^ ((r & 7) << 4));

  const float4 c0 = *reinterpret_cast<const float4*>(ctx + (size_t)n * DIM + d0);
  const float4 c1 = *reinterpret_cast<const float4*>(ctx + (size_t)n * DIM + d0 + 4);

#pragma unroll
  for (int p = 0; p < NPERS; ++p) {
    const float4 w0 = *reinterpret_cast<const float4*>(w + (size_t)p * DIM + d0);
    const float4 w1 = *reinterpret_cast<const float4*>(w + (size_t)p * DIM + d0 + 4);
    const float sc = invr[(size_t)p * N_CTX + n];

    float f[8] = {c0.x * w0.x * sc, c0.y * w0.y * sc, c0.z * w0.z * sc, c0.w * w0.w * sc,
                  c1.x * w1.x * sc, c1.y * w1.y * sc, c1.z * w1.z * sc, c1.w * w1.w * sc};
    if (F32) {
      float* dst = F32 + (size_t)n * KTOT + p * DIM + d0;
      *reinterpret_cast<float4*>(dst) = make_float4(f[0], f[1], f[2], f[3]);
      *reinterpret_cast<float4*>(dst + 4) = make_float4(f[4], f[5], f[6], f[7]);
    }
    unsigned hb[8], lb[8];
#pragma unroll
    for (int j = 0; j < 8; ++j) {
      hb[j] = f2bf(f[j]);
      float hf = __uint_as_float(hb[j] << 16);
      lb[j] = f2bf(f[j] - hf);
    }
    uint4 hv = make_uint4(hb[0] | (hb[1] << 16), hb[2] | (hb[3] << 16),
                          hb[4] | (hb[5] << 16), hb[6] | (hb[7] << 16));
    uint4 lv = make_uint4(lb[0] | (lb[1] << 16), lb[2] | (lb[3] << 16),
                          lb[4] | (lb[5] << 16), lb[6] | (lb[7] << 16));
    const int s = p * 8 + (db >> 3);      // k-step index
    const size_t base = (size_t)(P * 128 + s) * CHUNK + swzoff;
    *reinterpret_cast<uint4*>((char*)Fhi + base) = hv;
    *reinterpret_cast<uint4*>((char*)Flo + base) = lv;
  }
}

// ---------------------------------------------------------------------------
// Kernel 2 (fast): att = F F^T via bf16 MFMA, 3 products (hh, hl, lh).
// UNCHANGED from R10/R11 (496 us, MfmaUtil 38%, validated).
// ---------------------------------------------------------------------------
__global__ __launch_bounds__(256, 2) void att_gemm_fast(
    const unsigned short* __restrict__ Fhi, const unsigned short* __restrict__ Flo,
    float* __restrict__ out) {
  int bid = blockIdx.x;
  int by = 0;
  while (bid >= (by + 1) * 32 - ((by + 1) * by) / 2) ++by;
  const int bx = by + (bid - (by * 32 - (by * (by - 1)) / 2));

  __shared__ __align__(16) char Ahi[CHUNK];
  __shared__ __align__(16) char Alo[CHUNK];
  __shared__ __align__(16) char Bhi[CHUNK];
  __shared__ __align__(16) char Blo[CHUNK];

  const int t = threadIdx.x;
  const int lane = t & 63, wid = t >> 6;
  const int wr = wid >> 1, wc = wid & 1;
  const int woff = __builtin_amdgcn_readfirstlane(wid * 4096);

  const char* gAh = (const char*)Fhi + (size_t)by * NKSTEP * CHUNK + woff;
  const char* gAl = (const char*)Flo + (size_t)by * NKSTEP * CHUNK + woff;
  const char* gBh = (const char*)Fhi + (size_t)bx * NKSTEP * CHUNK + woff;
  const char* gBl = (const char*)Flo + (size_t)bx * NKSTEP * CHUNK + woff;

  f32x4 acc[4][4] = {};

  for (int s = 0; s < NKSTEP; ++s) {
    const size_t so = (size_t)s * CHUNK;
#pragma unroll
    for (int i = 0; i < 4; ++i) {
      stage1k(gAh + so + i * 1024, Ahi + woff + i * 1024, lane);
      stage1k(gAl + so + i * 1024, Alo + woff + i * 1024, lane);
      stage1k(gBh + so + i * 1024, Bhi + woff + i * 1024, lane);
      stage1k(gBl + so + i * 1024, Blo + woff + i * 1024, lane);
    }
    __syncthreads();   // vmcnt drained before barrier: staged data visible

#pragma unroll
    for (int ks = 0; ks < 2; ++ks) {
      const int kb = ks * 64 + (lane >> 4) * 16;
      bfrag ah[4], al[4], bh[4], bl[4];
#pragma unroll
      for (int m = 0; m < 4; ++m) {
        const int r = wr * 64 + m * 16 + (lane & 15);
        const int off = r * 128 + SWZ(r, kb);
        ah[m] = *reinterpret_cast<const bfrag*>(Ahi + off);
        al[m] = *reinterpret_cast<const bfrag*>(Alo + off);
      }
#pragma unroll
      for (int n2 = 0; n2 < 4; ++n2) {
        const int r = wc * 64 + n2 * 16 + (lane & 15);
        const int off = r * 128 + SWZ(r, kb);
        bh[n2] = *reinterpret_cast<const bfrag*>(Bhi + off);
        bl[n2] = *reinterpret_cast<const bfrag*>(Blo + off);
      }
#pragma unroll
      for (int m = 0; m < 4; ++m)
#pragma unroll
        for (int n2 = 0; n2 < 4; ++n2) {
          acc[m][n2] = __builtin_amdgcn_mfma_f32_16x16x32_bf16(ah[m], bh[n2], acc[m][n2], 0, 0, 0);
          acc[m][n2] = __builtin_amdgcn_mfma_f32_16x16x32_bf16(ah[m], bl[n2], acc[m][n2], 0, 0, 0);
          acc[m][n2] = __builtin_amdgcn_mfma_f32_16x16x32_bf16(al[m], bh[n2], acc[m][n2], 0, 0, 0);
        }
    }
    __syncthreads();   // all waves done reading before next overwrite
  }

  const int Ro = by * BM, Co = bx * BM;
  const int col = lane & 15, rq = (lane >> 4) * 4;
#pragma unroll
  for (int m = 0; m < 4; ++m)
#pragma unroll
    for (int n2 = 0; n2 < 4; ++n2) {
      const int gr = Ro + wr * 64 + m * 16 + rq;
      const int gc = Co + wc * 64 + n2 * 16 + col;
#pragma unroll
      for (int j = 0; j < 4; ++j)
        out[(size_t)(gr + j) * N_CTX + gc] = acc[m][n2][j];
      if (bx != by) {
        *reinterpret_cast<float4*>(out + (size_t)gc * N_CTX + gr) =
            make_float4(acc[m][n2][0], acc[m][n2][1], acc[m][n2][2], acc[m][n2][3]);
      }
    }
}

// ---------------------------------------------------------------------------
// Kernel 2 (fallback): on-the-fly split + MFMA (used only if ws too small).
// ---------------------------------------------------------------------------
__device__ __forceinline__ void stage_half(char* __restrict__ hi_base,
                                           char* __restrict__ lo_base,
                                           const float4* cv, const float4* wv,
                                           float s, int r, int h) {
  unsigned hu[16], lu[16];
#pragma unroll
  for (int i = 0; i < 8; ++i) {
    float f[4] = {cv[i].x * wv[i].x * s, cv[i].y * wv[i].y * s,
                  cv[i].z * wv[i].z * s, cv[i].w * wv[i].w * s};
    unsigned hb[4], lb[4];
#pragma unroll
    for (int j = 0; j < 4; ++j) {
      hb[j] = f2bf(f[j]);
      float hf = __uint_as_float(hb[j] << 16);
      lb[j] = f2bf(f[j] - hf);
    }
    hu[2 * i] = hb[0] | (hb[1] << 16);
    hu[2 * i + 1] = hb[2] | (hb[3] << 16);
    lu[2 * i] = lb[0] | (lb[1] << 16);
    lu[2 * i + 1] = lb[2] | (lb[3] << 16);
  }
#pragma unroll
  for (int c = 0; c < 4; ++c) {
    int boff = r * 128 + SWZ(r, h * 64 + c * 16);
    *reinterpret_cast<uint4*>(hi_base + boff) =
        make_uint4(hu[4 * c], hu[4 * c + 1], hu[4 * c + 2], hu[4 * c + 3]);
    *reinterpret_cast<uint4*>(lo_base + boff) =
        make_uint4(lu[4 * c], lu[4 * c + 1], lu[4 * c + 2], lu[4 * c + 3]);
  }
}

__global__ __launch_bounds__(256, 2) void att_gemm(
    const float* __restrict__ ctx, const float* __restrict__ w,
    const float* __restrict__ invr, float* __restrict__ out) {
  const int bx = blockIdx.x, by = blockIdx.y;
  if (by > bx) return;

  __shared__ __align__(16) char Ahi[BM * 128];
  __shared__ __align__(16) char Alo[BM * 128];
  __shared__ __align__(16) char Bhi[BM * 128];
  __shared__ __align__(16) char Blo[BM * 128];

  const int t = threadIdx.x;
  const int lane = t & 63, wid = t >> 6;
  const int wr = wid >> 1, wc = wid & 1;
  const int Ro = by * BM, Co = bx * BM;
  const int srow = t >> 1;
  const int sh = t & 1;

  f32x4 acc[4][4] = {};

  for (int k0 = 0; k0 < KTOT; k0 += BK) {
    const int p = k0 >> 9;
    const int d0 = (k0 & (DIM - 1)) + sh * 32;

    float4 cva[8], cvb[8], wv[8];
    const float* wrow = w + (size_t)p * DIM + d0;
    const float* arow = ctx + (size_t)(Ro + srow) * DIM + d0;
    const float* brow = ctx + (size_t)(Co + srow) * DIM + d0;
#pragma unroll
    for (int i = 0; i < 8; ++i) {
      wv[i] = *reinterpret_cast<const float4*>(wrow + 4 * i);
      cva[i] = *reinterpret_cast<const float4*>(arow + 4 * i);
      cvb[i] = *reinterpret_cast<const float4*>(brow + 4 * i);
    }
    const float sA = invr[(size_t)p * N_CTX + Ro + srow];
    const float sB = invr[(size_t)p * N_CTX + Co + srow];

    __syncthreads();
    stage_half(Ahi, Alo, cva, wv, sA, srow, sh);
    stage_half(Bhi, Blo, cvb, wv, sB, srow, sh);
    __syncthreads();

#pragma unroll
    for (int ks = 0; ks < 2; ++ks) {
      const int kb = ks * 64 + (lane >> 4) * 16;
      bfrag ah[4], al[4], bh[4], bl[4];
#pragma unroll
      for (int m = 0; m < 4; ++m) {
        const int r = wr * 64 + m * 16 + (lane & 15);
        const int off = r * 128 + SWZ(r, kb);
        ah[m] = *reinterpret_cast<const bfrag*>(Ahi + off);
        al[m] = *reinterpret_cast<const bfrag*>(Alo + off);
      }
#pragma unroll
      for (int n = 0; n < 4; ++n) {
        const int r = wc * 64 + n * 16 + (lane & 15);
        const int off = r * 128 + SWZ(r, kb);
        bh[n] = *reinterpret_cast<const bfrag*>(Bhi + off);
        bl[n] = *reinterpret_cast<const bfrag*>(Blo + off);
      }
#pragma unroll
      for (int m = 0; m < 4; ++m)
#pragma unroll
        for (int n = 0; n < 4; ++n) {
          acc[m][n] = __builtin_amdgcn_mfma_f32_16x16x32_bf16(ah[m], bh[n], acc[m][n], 0, 0, 0);
          acc[m][n] = __builtin_amdgcn_mfma_f32_16x16x32_bf16(ah[m], bl[n], acc[m][n], 0, 0, 0);
          acc[m][n] = __builtin_amdgcn_mfma_f32_16x16x32_bf16(al[m], bh[n], acc[m][n], 0, 0, 0);
        }
    }
  }

  const int col = lane & 15, rq = (lane >> 4) * 4;
#pragma unroll
  for (int m = 0; m < 4; ++m)
#pragma unroll
    for (int n = 0; n < 4; ++n) {
      const int gr = Ro + wr * 64 + m * 16 + rq;
      const int gc = Co + wc * 64 + n * 16 + col;
#pragma unroll
      for (int j = 0; j < 4; ++j)
        out[(size_t)(gr + j) * N_CTX + gc] = acc[m][n][j];
      if (bx != by) {
        *reinterpret_cast<float4*>(out + (size_t)gc * N_CTX + gr) =
            make_float4(acc[m][n][0], acc[m][n][1], acc[m][n][2], acc[m][n][3]);
      }
    }
}

// ---------------------------------------------------------------------------
// Kernel 3: scan (separate again — R12 fusion regressed). Coalesced mapping:
// thread t owns float4s at (blk*256 + t); every wave load/store is 64x16B
// contiguous. Classification semantics identical to R11/R12 (mask-invariant);
// DELTA shrunk 1e-3 -> 3e-4 (still >=12x the 2*eps classification bound).
// ---------------------------------------------------------------------------
__global__ __launch_bounds__(256) void topk_scan(
    float* __restrict__ att, int* __restrict__ candM,
    int* __restrict__ cnt_g) {
  __shared__ unsigned red[4];
  __shared__ int lcnt, lg;

  const int n = blockIdx.x;
  const int t = threadIdx.x;
  const int wid = t >> 6, lane = t & 63;
  float* row = att + (size_t)n * N_CTX;

  float ar[16], tr[16];
  unsigned ur[16];
#pragma unroll
  for (int i = 0; i < 4; ++i) {
    float4 v4 = *reinterpret_cast<const float4*>(row + (size_t)(i * 256 + t) * 4);
    float tmp[4] = {v4.x, v4.y, v4.z, v4.w};
#pragma unroll
    for (int j = 0; j < 4; ++j) {
      float a = tmp[j];
      float tt = (a > EPS_NN) ? a : 0.0f;
      ar[i * 4 + j] = a;
      tr[i * 4 + j] = tt;
      ur[i * 4 + j] = __float_as_uint(tt);
    }
  }

  // binary search: smallest u with count(bits > u) < K  => u = bits(30th)
  unsigned lo = 0u, hi = 0x7F800000u;
  while (lo < hi) {
    unsigned mid = lo + ((hi - lo) >> 1);
    unsigned c = 0;
#pragma unroll
    for (int i = 0; i < 16; ++i) c += (ur[i] > mid) ? 1u : 0u;
#pragma unroll
    for (int off = 32; off; off >>= 1) c += __shfl_down(c, off, 64);
    if (lane == 0) red[wid] = c;
    __syncthreads();
    unsigned tot = red[0] + red[1] + red[2] + red[3];
    __syncthreads();
    if (tot < TOPK_K) hi = mid; else lo = mid + 1;
  }
  const float vk = __uint_as_float(lo);
  const bool nearEps = (vk <= EPS_NN + 2.0f * DELTA);

  if (t == 0) { lcnt = 0; lg = 0; }
  __syncthreads();

  unsigned myg = 0;
#pragma unroll
  for (int i = 0; i < 16; ++i) {
    const int blk = i >> 2, j = i & 3;
    const int m = (blk * 256 + t) * 4 + j;
    const float a = ar[i], tt = tr[i];
    const bool isEps = fabsf(a - EPS_NN) <= DELTA;
    const bool isOrd = (tt > 0.f) && (fabsf(tt - vk) <= DELTA);
    const bool cand = isOrd || (isEps && nearEps);
    const bool defIn = (tt > vk + DELTA) && !cand;
    tr[i] = defIn ? tt : 0.f;
    myg += defIn ? 1u : 0u;
    if (cand) {
      int pos = atomicAdd(&lcnt, 1);
      if (pos < CAP) candM[n * CAP + pos] = m;
    }
  }
#pragma unroll
  for (int off = 32; off; off >>= 1) myg += __shfl_down(myg, off, 64);
  if (lane == 0) atomicAdd(&lg, (int)myg);

#pragma unroll
  for (int i = 0; i < 4; ++i) {
    *reinterpret_cast<float4*>(row + (size_t)(i * 256 + t) * 4) =
        make_float4(tr[i * 4], tr[i * 4 + 1], tr[i * 4 + 2], tr[i * 4 + 3]);
  }
  __syncthreads();
  if (t == 0) {
    cnt_g[2 * n] = (lcnt < CAP) ? lcnt : CAP;
    cnt_g[2 * n + 1] = lg;
  }
}

// ---------------------------------------------------------------------------
// Kernel 4: exact repair + select (separate, 1-wave blocks, early exit).
// R13: if F32 (the materialized (c*w)*s values) is available, the chain is
// e = fmaf(Fa[k], Fb[k], e), k ascending — IDENTICAL values and summation
// order to R2's LDS-staged chain -> bit-identical. Else ctx-chain (verbatim).
// ---------------------------------------------------------------------------
__global__ __launch_bounds__(64) void repair_select(
    const float* __restrict__ ctx, const float* __restrict__ w,
    const float* __restrict__ invr, const float* __restrict__ F32,
    const int* __restrict__ candM, const int* __restrict__ cnt_g,
    float* __restrict__ att) {
  const int n = blockIdx.x;
  const int c = cnt_g[2 * n];
  if (c == 0) return;
  const int slots = TOPK_K - cnt_g[2 * n + 1];

  __shared__ float te_s[CAP];
  __shared__ int m_s[CAP];

  const int j = threadIdx.x;
  float te = -1.f;
  int m = -1;
  if (j < c) {
    m = candM[n * CAP + j];
    float e = 0.f;
    if (F32) {
      const float4* fa4 = reinterpret_cast<const float4*>(F32 + (size_t)n * KTOT);
      const float4* fb4 = reinterpret_cast<const float4*>(F32 + (size_t)m * KTOT);
#pragma unroll 8
      for (int q = 0; q < KTOT / 4; ++q) {
        const float4 a = fa4[q], b = fb4[q];
        e = fmaf(a.x, b.x, e);
        e = fmaf(a.y, b.y, e);
        e = fmaf(a.z, b.z, e);
        e = fmaf(a.w, b.w, e);
      }
    } else {
      const float4* cn4 = reinterpret_cast<const float4*>(ctx + (size_t)n * DIM);
      const float4* cm4 = reinterpret_cast<const float4*>(ctx + (size_t)m * DIM);
      for (int p = 0; p < NPERS; ++p) {
        const float sA = invr[(size_t)p * N_CTX + n];
        const float sB = invr[(size_t)p * N_CTX + m];
        const float4* w4 = reinterpret_cast<const float4*>(w + (size_t)p * DIM);
#pragma unroll 4
        for (int q = 0; q < DIM / 4; ++q) {
          const float4 a = cn4[q], b = cm4[q], ww = w4[q];
          e = fmaf((a.x * ww.x) * sA, (b.x * ww.x) * sB, e);
          e = fmaf((a.y * ww.y) * sA, (b.y * ww.y) * sB, e);
          e = fmaf((a.z * ww.z) * sA, (b.z * ww.z) * sB, e);
          e = fmaf((a.w * ww.w) * sA, (b.w * ww.w) * sB, e);
        }
      }
    }
    te = (e > EPS_NN) ? e : 0.f;
  }
  m_s[j] = m;
  te_s[j] = te;
  __syncthreads();
  if (j < c) {
    int rank = 0;
    for (int i = 0; i < c; ++i) {
      if (i == j) continue;
      rank += ((te_s[i] > te) || (te_s[i] == te && m_s[i] < m)) ? 1 : 0;
    }
    if (rank < slots) att[(size_t)n * N_CTX + m] = te;
  }
}

// ---------------------------------------------------------------------------
extern "C" void kernel_launch(void* const* d_in, const int* in_sizes, int n_in,
                              void* d_out, int out_size, void* d_ws, size_t ws_size,
                              hipStream_t stream) {
  const float* ctx = (const float*)d_in[0];   // (4096, 512)
  const float* w   = (const float*)d_in[1];   // (16, 512)
  float* out = (float*)d_out;                 // (4096, 4096)

  // ws: invr 256KB | cnt_g 32KB | candM 1MB | Fhi 64MB | Flo 64MB | F32 128MB
  const size_t OFF_CNT = 262144;
  const size_t OFF_CAND = OFF_CNT + 32768;
  const size_t OFF_FHI = OFF_CAND + 1048576;
  const size_t FSZ = (size_t)32 * NKSTEP * CHUNK;       // 67108864
  const size_t OFF_F32 = OFF_FHI + 2 * FSZ;
  const size_t F32SZ = (size_t)N_CTX * KTOT * sizeof(float);  // 134217728
  float* invr = (float*)d_ws;
  int* cnt_g = (int*)((char*)d_ws + OFF_CNT);
  int* candM = (int*)((char*)d_ws + OFF_CAND);
  unsigned short* Fhi = (unsigned short*)((char*)d_ws + OFF_FHI);
  unsigned short* Flo = (unsigned short*)((char*)d_ws + OFF_FHI + FSZ);
  const bool haveF = ws_size >= OFF_FHI + 2 * FSZ;
  const bool haveF32 = ws_size >= OFF_F32 + F32SZ;
  float* F32 = haveF32 ? (float*)((char*)d_ws + OFF_F32) : nullptr;

  norms_kernel<<<(NPERS * N_CTX) / 4, 256, 0, stream>>>(ctx, w, invr);

  if (haveF) {
    split_kernel<<<(N_CTX * 64) / 256, 256, 0, stream>>>(ctx, w, invr, Fhi, Flo, F32);
    att_gemm_fast<<<528, 256, 0, stream>>>(Fhi, Flo, out);
  } else {
    dim3 grid(N_CTX / BM, N_CTX / BM);
    att_gemm<<<grid, 256, 0, stream>>>(ctx, w, invr, out);
  }

  topk_scan<<<N_CTX, 256, 0, stream>>>(out, candM, cnt_g);
  repair_select<<<N_CTX, 64, 0, stream>>>(ctx, w, invr, F32, candM, cnt_g, out);
}

// Round 14
// 1010.412 us; speedup vs baseline: 1.1357x; 1.0144x over previous
//
#include <hip/hip_runtime.h>
#include <math.h>
#include <stdint.h>

#define N_CTX 4096
#define DIM 512
#define NPERS 16
#define KTOT (NPERS * DIM)   // 8192
#define EPS_NN 0.1f
#define TOPK_K 30

#define DELTA 3e-4f          // ambiguity margin (>= 12x the 2*eps ~ 2.4e-5 bound)
#define CAP 64               // max candidates per row

#define BM 128               // MFMA output tile
#define BK 64                // K-step (bf16 elems)
#define NKSTEP (KTOT / BK)   // 128
#define CHUNK 16384          // bytes per (panel, k-step) LDS image

typedef __attribute__((ext_vector_type(8))) short bfrag;   // 8 bf16 = 4 VGPR
typedef __attribute__((ext_vector_type(4))) float f32x4;

// round-to-nearest-even float -> bf16 bits
__device__ __forceinline__ unsigned short f2bf(float f) {
  unsigned u = __float_as_uint(f);
  unsigned r = u + 0x7FFFu + ((u >> 16) & 1u);
  return (unsigned short)(r >> 16);
}

#define SWZ(r, b) ((b) ^ (((r) & 7) << 4))

// stage 1 KB: 64 lanes x 16 B. ldst = wave-uniform LDS base; HW adds lane*16.
__device__ __forceinline__ void stage1k(const char* gsrc, char* ldst, int lane) {
#if __has_builtin(__builtin_amdgcn_global_load_lds)
  __builtin_amdgcn_global_load_lds(
      (const __attribute__((address_space(1))) unsigned int*)(uintptr_t)(gsrc + lane * 16),
      (__attribute__((address_space(3))) unsigned int*)(uintptr_t)ldst, 16, 0, 0);
#else
  *reinterpret_cast<uint4*>(ldst + lane * 16) =
      *reinterpret_cast<const uint4*>(gsrc + lane * 16);
#endif
}

// ---------------------------------------------------------------------------
// Kernel 1 (fallback only): invr[p][n] = 0.25 / max(||c_n * w_p||, 1e-12)
// ---------------------------------------------------------------------------
__global__ __launch_bounds__(256) void norms_kernel(
    const float* __restrict__ ctx, const float* __restrict__ w,
    float* __restrict__ invr) {
  int wid = threadIdx.x >> 6;
  int lane = threadIdx.x & 63;
  int gid = blockIdx.x * 4 + wid;          // 0 .. 65535
  int p = gid >> 12;
  int n = gid & (N_CTX - 1);
  const float4* c4 = reinterpret_cast<const float4*>(ctx + (size_t)n * DIM + lane * 8);
  const float4* w4 = reinterpret_cast<const float4*>(w + (size_t)p * DIM + lane * 8);
  float4 c0 = c4[0], c1 = c4[1];
  float4 w0 = w4[0], w1 = w4[1];
  float s = 0.f, v;
  v = c0.x * w0.x; s = fmaf(v, v, s);
  v = c0.y * w0.y; s = fmaf(v, v, s);
  v = c0.z * w0.z; s = fmaf(v, v, s);
  v = c0.w * w0.w; s = fmaf(v, v, s);
  v = c1.x * w1.x; s = fmaf(v, v, s);
  v = c1.y * w1.y; s = fmaf(v, v, s);
  v = c1.z * w1.z; s = fmaf(v, v, s);
  v = c1.w * w1.w; s = fmaf(v, v, s);
#pragma unroll
  for (int off = 32; off; off >>= 1) s += __shfl_down(s, off, 64);
  if (lane == 0) invr[(size_t)p * N_CTX + n] = 0.25f / fmaxf(sqrtf(s), 1e-12f);
}

// ---------------------------------------------------------------------------
// Kernel 1+1b FUSED: per wave = one row n (64 lanes x 8 cols). For each p:
// compute prod = c*w (lane-local, same RNE products as norms_kernel), norm
// via the IDENTICAL fmaf chain + identical __shfl_down tree, broadcast,
// sc = 0.25/max(sqrt,1e-12) (identical expression) -> invr bit-identical.
// Then f = prod*sc (identical to prior split: (c*w)*sc), bf16 hi/lo split,
// store into panel-swizzled LDS image. Saves norms_kernel's 128 MB re-read.
// ---------------------------------------------------------------------------
__global__ __launch_bounds__(256) void split_norms_kernel(
    const float* __restrict__ ctx, const float* __restrict__ w,
    float* __restrict__ invr, unsigned short* __restrict__ Fhi,
    unsigned short* __restrict__ Flo) {
  const int tid = blockIdx.x * 256 + threadIdx.x;   // 0 .. 4096*64-1
  const int n = tid >> 6;                 // wave-uniform (wave = 64 aligned)
  const int db = tid & 63;                // lane = 8-col block within 512-dim
  const int d0 = db * 8;
  const int P = n >> 7;                   // panel
  const int r = n & 127;                  // row within panel
  const int sl = db & 7;                  // 16B slot within k-step chunk
  const int swzoff = r * 128 + ((sl * 16) ^ ((r & 7) << 4));

  const float4 c0 = *reinterpret_cast<const float4*>(ctx + (size_t)n * DIM + d0);
  const float4 c1 = *reinterpret_cast<const float4*>(ctx + (size_t)n * DIM + d0 + 4);

#pragma unroll
  for (int p = 0; p < NPERS; ++p) {
    const float4 w0 = *reinterpret_cast<const float4*>(w + (size_t)p * DIM + d0);
    const float4 w1 = *reinterpret_cast<const float4*>(w + (size_t)p * DIM + d0 + 4);

    // lane-local products (same RNE muls as norms_kernel's v's and the old
    // split's (c*w) intermediates)
    float pr[8] = {c0.x * w0.x, c0.y * w0.y, c0.z * w0.z, c0.w * w0.w,
                   c1.x * w1.x, c1.y * w1.y, c1.z * w1.z, c1.w * w1.w};

    // norm: identical fmaf order + identical reduce tree as norms_kernel
    float s = 0.f;
#pragma unroll
    for (int j = 0; j < 8; ++j) s = fmaf(pr[j], pr[j], s);
#pragma unroll
    for (int off = 32; off; off >>= 1) s += __shfl_down(s, off, 64);
    const float stot = __shfl(s, 0, 64);          // lane-0 total, broadcast
    const float sc = 0.25f / fmaxf(sqrtf(stot), 1e-12f);
    if (db == 0) invr[(size_t)p * N_CTX + n] = sc;

    unsigned hb[8], lb[8];
#pragma unroll
    for (int j = 0; j < 8; ++j) {
      const float f = pr[j] * sc;                  // == (c*w)*sc, as before
      hb[j] = f2bf(f);
      float hf = __uint_as_float(hb[j] << 16);
      lb[j] = f2bf(f - hf);
    }
    uint4 hv = make_uint4(hb[0] | (hb[1] << 16), hb[2] | (hb[3] << 16),
                          hb[4] | (hb[5] << 16), hb[6] | (hb[7] << 16));
    uint4 lv = make_uint4(lb[0] | (lb[1] << 16), lb[2] | (lb[3] << 16),
                          lb[4] | (lb[5] << 16), lb[6] | (lb[7] << 16));
    const int kstep = p * 8 + (db >> 3);           // k-step index
    const size_t base = (size_t)(P * 128 + kstep) * CHUNK + swzoff;
    *reinterpret_cast<uint4*>((char*)Fhi + base) = hv;
    *reinterpret_cast<uint4*>((char*)Flo + base) = lv;
  }
}

// ---------------------------------------------------------------------------
// Kernel 2 (fast): att = F F^T via bf16 MFMA, 3 products (hh, hl, lh).
// R14: bijective XCD swizzle (528 = 8*66) — each XCD gets 66 consecutive
// triangular tiles sharing the A-panel (4 MB ~ one L2). Per-tile arithmetic
// unchanged -> att values bit-identical.
// ---------------------------------------------------------------------------
__global__ __launch_bounds__(256, 2) void att_gemm_fast(
    const unsigned short* __restrict__ Fhi, const unsigned short* __restrict__ Flo,
    float* __restrict__ out) {
  const int bid0 = blockIdx.x;
  int bid = (bid0 & 7) * 66 + (bid0 >> 3);   // XCD-contiguous tile runs
  int by = 0;
  while (bid >= (by + 1) * 32 - ((by + 1) * by) / 2) ++by;
  const int bx = by + (bid - (by * 32 - (by * (by - 1)) / 2));

  __shared__ __align__(16) char Ahi[CHUNK];
  __shared__ __align__(16) char Alo[CHUNK];
  __shared__ __align__(16) char Bhi[CHUNK];
  __shared__ __align__(16) char Blo[CHUNK];

  const int t = threadIdx.x;
  const int lane = t & 63, wid = t >> 6;
  const int wr = wid >> 1, wc = wid & 1;
  const int woff = __builtin_amdgcn_readfirstlane(wid * 4096);

  const char* gAh = (const char*)Fhi + (size_t)by * NKSTEP * CHUNK + woff;
  const char* gAl = (const char*)Flo + (size_t)by * NKSTEP * CHUNK + woff;
  const char* gBh = (const char*)Fhi + (size_t)bx * NKSTEP * CHUNK + woff;
  const char* gBl = (const char*)Flo + (size_t)bx * NKSTEP * CHUNK + woff;

  f32x4 acc[4][4] = {};

  for (int s = 0; s < NKSTEP; ++s) {
    const size_t so = (size_t)s * CHUNK;
#pragma unroll
    for (int i = 0; i < 4; ++i) {
      stage1k(gAh + so + i * 1024, Ahi + woff + i * 1024, lane);
      stage1k(gAl + so + i * 1024, Alo + woff + i * 1024, lane);
      stage1k(gBh + so + i * 1024, Bhi + woff + i * 1024, lane);
      stage1k(gBl + so + i * 1024, Blo + woff + i * 1024, lane);
    }
    __syncthreads();   // vmcnt drained before barrier: staged data visible

#pragma unroll
    for (int ks = 0; ks < 2; ++ks) {
      const int kb = ks * 64 + (lane >> 4) * 16;
      bfrag ah[4], al[4], bh[4], bl[4];
#pragma unroll
      for (int m = 0; m < 4; ++m) {
        const int r = wr * 64 + m * 16 + (lane & 15);
        const int off = r * 128 + SWZ(r, kb);
        ah[m] = *reinterpret_cast<const bfrag*>(Ahi + off);
        al[m] = *reinterpret_cast<const bfrag*>(Alo + off);
      }
#pragma unroll
      for (int n2 = 0; n2 < 4; ++n2) {
        const int r = wc * 64 + n2 * 16 + (lane & 15);
        const int off = r * 128 + SWZ(r, kb);
        bh[n2] = *reinterpret_cast<const bfrag*>(Bhi + off);
        bl[n2] = *reinterpret_cast<const bfrag*>(Blo + off);
      }
#pragma unroll
      for (int m = 0; m < 4; ++m)
#pragma unroll
        for (int n2 = 0; n2 < 4; ++n2) {
          acc[m][n2] = __builtin_amdgcn_mfma_f32_16x16x32_bf16(ah[m], bh[n2], acc[m][n2], 0, 0, 0);
          acc[m][n2] = __builtin_amdgcn_mfma_f32_16x16x32_bf16(ah[m], bl[n2], acc[m][n2], 0, 0, 0);
          acc[m][n2] = __builtin_amdgcn_mfma_f32_16x16x32_bf16(al[m], bh[n2], acc[m][n2], 0, 0, 0);
        }
    }
    __syncthreads();   // all waves done reading before next overwrite
  }

  const int Ro = by * BM, Co = bx * BM;
  const int col = lane & 15, rq = (lane >> 4) * 4;
#pragma unroll
  for (int m = 0; m < 4; ++m)
#pragma unroll
    for (int n2 = 0; n2 < 4; ++n2) {
      const int gr = Ro + wr * 64 + m * 16 + rq;
      const int gc = Co + wc * 64 + n2 * 16 + col;
#pragma unroll
      for (int j = 0; j < 4; ++j)
        out[(size_t)(gr + j) * N_CTX + gc] = acc[m][n2][j];
      if (bx != by) {
        *reinterpret_cast<float4*>(out + (size_t)gc * N_CTX + gr) =
            make_float4(acc[m][n2][0], acc[m][n2][1], acc[m][n2][2], acc[m][n2][3]);
      }
    }
}

// ---------------------------------------------------------------------------
// Kernel 2 (fallback): on-the-fly split + MFMA (used only if ws too small).
// ---------------------------------------------------------------------------
__device__ __forceinline__ void stage_half(char* __restrict__ hi_base,
                                           char* __restrict__ lo_base,
                                           const float4* cv, const float4* wv,
                                           float s, int r, int h) {
  unsigned hu[16], lu[16];
#pragma unroll
  for (int i = 0; i < 8; ++i) {
    float f[4] = {cv[i].x * wv[i].x * s, cv[i].y * wv[i].y * s,
                  cv[i].z * wv[i].z * s, cv[i].w * wv[i].w * s};
    unsigned hb[4], lb[4];
#pragma unroll
    for (int j = 0; j < 4; ++j) {
      hb[j] = f2bf(f[j]);
      float hf = __uint_as_float(hb[j] << 16);
      lb[j] = f2bf(f[j] - hf);
    }
    hu[2 * i] = hb[0] | (hb[1] << 16);
    hu[2 * i + 1] = hb[2] | (hb[3] << 16);
    lu[2 * i] = lb[0] | (lb[1] << 16);
    lu[2 * i + 1] = lb[2] | (lb[3] << 16);
  }
#pragma unroll
  for (int c = 0; c < 4; ++c) {
    int boff = r * 128 + SWZ(r, h * 64 + c * 16);
    *reinterpret_cast<uint4*>(hi_base + boff) =
        make_uint4(hu[4 * c], hu[4 * c + 1], hu[4 * c + 2], hu[4 * c + 3]);
    *reinterpret_cast<uint4*>(lo_base + boff) =
        make_uint4(lu[4 * c], lu[4 * c + 1], lu[4 * c + 2], lu[4 * c + 3]);
  }
}

__global__ __launch_bounds__(256, 2) void att_gemm(
    const float* __restrict__ ctx, const float* __restrict__ w,
    const float* __restrict__ invr, float* __restrict__ out) {
  const int bx = blockIdx.x, by = blockIdx.y;
  if (by > bx) return;

  __shared__ __align__(16) char Ahi[BM * 128];
  __shared__ __align__(16) char Alo[BM * 128];
  __shared__ __align__(16) char Bhi[BM * 128];
  __shared__ __align__(16) char Blo[BM * 128];

  const int t = threadIdx.x;
  const int lane = t & 63, wid = t >> 6;
  const int wr = wid >> 1, wc = wid & 1;
  const int Ro = by * BM, Co = bx * BM;
  const int srow = t >> 1;
  const int sh = t & 1;

  f32x4 acc[4][4] = {};

  for (int k0 = 0; k0 < KTOT; k0 += BK) {
    const int p = k0 >> 9;
    const int d0 = (k0 & (DIM - 1)) + sh * 32;

    float4 cva[8], cvb[8], wv[8];
    const float* wrow = w + (size_t)p * DIM + d0;
    const float* arow = ctx + (size_t)(Ro + srow) * DIM + d0;
    const float* brow = ctx + (size_t)(Co + srow) * DIM + d0;
#pragma unroll
    for (int i = 0; i < 8; ++i) {
      wv[i] = *reinterpret_cast<const float4*>(wrow + 4 * i);
      cva[i] = *reinterpret_cast<const float4*>(arow + 4 * i);
      cvb[i] = *reinterpret_cast<const float4*>(brow + 4 * i);
    }
    const float sA = invr[(size_t)p * N_CTX + Ro + srow];
    const float sB = invr[(size_t)p * N_CTX + Co + srow];

    __syncthreads();
    stage_half(Ahi, Alo, cva, wv, sA, srow, sh);
    stage_half(Bhi, Blo, cvb, wv, sB, srow, sh);
    __syncthreads();

#pragma unroll
    for (int ks = 0; ks < 2; ++ks) {
      const int kb = ks * 64 + (lane >> 4) * 16;
      bfrag ah[4], al[4], bh[4], bl[4];
#pragma unroll
      for (int m = 0; m < 4; ++m) {
        const int r = wr * 64 + m * 16 + (lane & 15);
        const int off = r * 128 + SWZ(r, kb);
        ah[m] = *reinterpret_cast<const bfrag*>(Ahi + off);
        al[m] = *reinterpret_cast<const bfrag*>(Alo + off);
      }
#pragma unroll
      for (int n = 0; n < 4; ++n) {
        const int r = wc * 64 + n * 16 + (lane & 15);
        const int off = r * 128 + SWZ(r, kb);
        bh[n] = *reinterpret_cast<const bfrag*>(Bhi + off);
        bl[n] = *reinterpret_cast<const bfrag*>(Blo + off);
      }
#pragma unroll
      for (int m = 0; m < 4; ++m)
#pragma unroll
        for (int n = 0; n < 4; ++n) {
          acc[m][n] = __builtin_amdgcn_mfma_f32_16x16x32_bf16(ah[m], bh[n], acc[m][n], 0, 0, 0);
          acc[m][n] = __builtin_amdgcn_mfma_f32_16x16x32_bf16(ah[m], bl[n], acc[m][n], 0, 0, 0);
          acc[m][n] = __builtin_amdgcn_mfma_f32_16x16x32_bf16(al[m], bh[n], acc[m][n], 0, 0, 0);
        }
    }
  }

  const int col = lane & 15, rq = (lane >> 4) * 4;
#pragma unroll
  for (int m = 0; m < 4; ++m)
#pragma unroll
    for (int n = 0; n < 4; ++n) {
      const int gr = Ro + wr * 64 + m * 16 + rq;
      const int gc = Co + wc * 64 + n * 16 + col;
#pragma unroll
      for (int j = 0; j < 4; ++j)
        out[(size_t)(gr + j) * N_CTX + gc] = acc[m][n][j];
      if (bx != by) {
        *reinterpret_cast<float4*>(out + (size_t)gc * N_CTX + gr) =
            make_float4(acc[m][n][0], acc[m][n][1], acc[m][n][2], acc[m][n][3]);
      }
    }
}

// ---------------------------------------------------------------------------
// Kernel 3: scan — UNCHANGED from R13 (coalesced mapping, DELTA 3e-4).
// ---------------------------------------------------------------------------
__global__ __launch_bounds__(256) void topk_scan(
    float* __restrict__ att, int* __restrict__ candM,
    int* __restrict__ cnt_g) {
  __shared__ unsigned red[4];
  __shared__ int lcnt, lg;

  const int n = blockIdx.x;
  const int t = threadIdx.x;
  const int wid = t >> 6, lane = t & 63;
  float* row = att + (size_t)n * N_CTX;

  float ar[16], tr[16];
  unsigned ur[16];
#pragma unroll
  for (int i = 0; i < 4; ++i) {
    float4 v4 = *reinterpret_cast<const float4*>(row + (size_t)(i * 256 + t) * 4);
    float tmp[4] = {v4.x, v4.y, v4.z, v4.w};
#pragma unroll
    for (int j = 0; j < 4; ++j) {
      float a = tmp[j];
      float tt = (a > EPS_NN) ? a : 0.0f;
      ar[i * 4 + j] = a;
      tr[i * 4 + j] = tt;
      ur[i * 4 + j] = __float_as_uint(tt);
    }
  }

  unsigned lo = 0u, hi = 0x7F800000u;
  while (lo < hi) {
    unsigned mid = lo + ((hi - lo) >> 1);
    unsigned c = 0;
#pragma unroll
    for (int i = 0; i < 16; ++i) c += (ur[i] > mid) ? 1u : 0u;
#pragma unroll
    for (int off = 32; off; off >>= 1) c += __shfl_down(c, off, 64);
    if (lane == 0) red[wid] = c;
    __syncthreads();
    unsigned tot = red[0] + red[1] + red[2] + red[3];
    __syncthreads();
    if (tot < TOPK_K) hi = mid; else lo = mid + 1;
  }
  const float vk = __uint_as_float(lo);
  const bool nearEps = (vk <= EPS_NN + 2.0f * DELTA);

  if (t == 0) { lcnt = 0; lg = 0; }
  __syncthreads();

  unsigned myg = 0;
#pragma unroll
  for (int i = 0; i < 16; ++i) {
    const int blk = i >> 2, j = i & 3;
    const int m = (blk * 256 + t) * 4 + j;
    const float a = ar[i], tt = tr[i];
    const bool isEps = fabsf(a - EPS_NN) <= DELTA;
    const bool isOrd = (tt > 0.f) && (fabsf(tt - vk) <= DELTA);
    const bool cand = isOrd || (isEps && nearEps);
    const bool defIn = (tt > vk + DELTA) && !cand;
    tr[i] = defIn ? tt : 0.f;
    myg += defIn ? 1u : 0u;
    if (cand) {
      int pos = atomicAdd(&lcnt, 1);
      if (pos < CAP) candM[n * CAP + pos] = m;
    }
  }
#pragma unroll
  for (int off = 32; off; off >>= 1) myg += __shfl_down(myg, off, 64);
  if (lane == 0) atomicAdd(&lg, (int)myg);

#pragma unroll
  for (int i = 0; i < 4; ++i) {
    *reinterpret_cast<float4*>(row + (size_t)(i * 256 + t) * 4) =
        make_float4(tr[i * 4], tr[i * 4 + 1], tr[i * 4 + 2], tr[i * 4 + 3]);
  }
  __syncthreads();
  if (t == 0) {
    cnt_g[2 * n] = (lcnt < CAP) ? lcnt : CAP;
    cnt_g[2 * n + 1] = lg;
  }
}

// ---------------------------------------------------------------------------
// Kernel 4: exact repair + select — R11 ctx-chain verbatim (bit-identical to
// the locked R2 chain: (cn*w)*sA vs (cm*w)*sB, k ascending via fmaf).
// ---------------------------------------------------------------------------
__global__ __launch_bounds__(64) void repair_select(
    const float* __restrict__ ctx, const float* __restrict__ w,
    const float* __restrict__ invr, const int* __restrict__ candM,
    const int* __restrict__ cnt_g, float* __restrict__ att) {
  const int n = blockIdx.x;
  const int c = cnt_g[2 * n];
  if (c == 0) return;
  const int slots = TOPK_K - cnt_g[2 * n + 1];

  __shared__ float te_s[CAP];
  __shared__ int m_s[CAP];

  const int j = threadIdx.x;
  float te = -1.f;
  int m = -1;
  if (j < c) {
    m = candM[n * CAP + j];
    const float4* cn4 = reinterpret_cast<const float4*>(ctx + (size_t)n * DIM);
    const float4* cm4 = reinterpret_cast<const float4*>(ctx + (size_t)m * DIM);
    float e = 0.f;
    for (int p = 0; p < NPERS; ++p) {
      const float sA = invr[(size_t)p * N_CTX + n];
      const float sB = invr[(size_t)p * N_CTX + m];
      const float4* w4 = reinterpret_cast<const float4*>(w + (size_t)p * DIM);
#pragma unroll 4
      for (int q = 0; q < DIM / 4; ++q) {
        const float4 a = cn4[q], b = cm4[q], ww = w4[q];
        e = fmaf((a.x * ww.x) * sA, (b.x * ww.x) * sB, e);
        e = fmaf((a.y * ww.y) * sA, (b.y * ww.y) * sB, e);
        e = fmaf((a.z * ww.z) * sA, (b.z * ww.z) * sB, e);
        e = fmaf((a.w * ww.w) * sA, (b.w * ww.w) * sB, e);
      }
    }
    te = (e > EPS_NN) ? e : 0.f;
  }
  m_s[j] = m;
  te_s[j] = te;
  __syncthreads();
  if (j < c) {
    int rank = 0;
    for (int i = 0; i < c; ++i) {
      if (i == j) continue;
      rank += ((te_s[i] > te) || (te_s[i] == te && m_s[i] < m)) ? 1 : 0;
    }
    if (rank < slots) att[(size_t)n * N_CTX + m] = te;
  }
}

// ---------------------------------------------------------------------------
extern "C" void kernel_launch(void* const* d_in, const int* in_sizes, int n_in,
                              void* d_out, int out_size, void* d_ws, size_t ws_size,
                              hipStream_t stream) {
  const float* ctx = (const float*)d_in[0];   // (4096, 512)
  const float* w   = (const float*)d_in[1];   // (16, 512)
  float* out = (float*)d_out;                 // (4096, 4096)

  // ws: invr 256KB | cnt_g 32KB | candM 1MB | Fhi 64MB | Flo 64MB
  const size_t OFF_CNT = 262144;
  const size_t OFF_CAND = OFF_CNT + 32768;
  const size_t OFF_FHI = OFF_CAND + 1048576;
  const size_t FSZ = (size_t)32 * NKSTEP * CHUNK;       // 67108864
  float* invr = (float*)d_ws;
  int* cnt_g = (int*)((char*)d_ws + OFF_CNT);
  int* candM = (int*)((char*)d_ws + OFF_CAND);
  unsigned short* Fhi = (unsigned short*)((char*)d_ws + OFF_FHI);
  unsigned short* Flo = (unsigned short*)((char*)d_ws + OFF_FHI + FSZ);
  const bool haveF = ws_size >= OFF_FHI + 2 * FSZ;

  if (haveF) {
    split_norms_kernel<<<(N_CTX * 64) / 256, 256, 0, stream>>>(ctx, w, invr, Fhi, Flo);
    att_gemm_fast<<<528, 256, 0, stream>>>(Fhi, Flo, out);
  } else {
    norms_kernel<<<(NPERS * N_CTX) / 4, 256, 0, stream>>>(ctx, w, invr);
    dim3 grid(N_CTX / BM, N_CTX / BM);
    att_gemm<<<grid, 256, 0, stream>>>(ctx, w, invr, out);
  }

  topk_scan<<<N_CTX, 256, 0, stream>>>(out, candM, cnt_g);
  repair_select<<<N_CTX, 64, 0, stream>>>(ctx, w, invr, candM, cnt_g, out);
}